// Round 1
// baseline (1000.024 us; speedup 1.0000x reference)
//
#include <hip/hip_runtime.h>
#include <math.h>

#define EPS 1e-5f

// ---------------- workspace layout (floats) ----------------
// [0, 7340032)            qkv buffer, later overwritten in-place with "so"
// [7340032, 7340032+560)  sums: qkv_sum[128] qkv_sq[128] | sim_sum[24] sim_sq[24] | out_sum[128] out_sq[128]
// [+560, +1120)           params: qkvP scale[128] shift[128] | simP scale[24] shift[24] | outP scale[128] shift[128]

// =============== K1: qkv = w @ x per block b, + stats ===============
__global__ __launch_bounds__(256) void k_qkv(const float* __restrict__ x,
                                             const float* __restrict__ w,
                                             float* __restrict__ qkv,
                                             float* __restrict__ sums) {
    const int b = blockIdx.x;
    const int s = b >> 5, wcol = b & 31;
    const int lane = threadIdx.x & 63;
    const int wave = __builtin_amdgcn_readfirstlane(threadIdx.x >> 6);
    const int i = (lane < 56) ? lane : 0;

    // x fragment in registers: xr[c] = x[0, c, s, i, wcol]
    float xr[64];
    const float* xp = x + (size_t)s * 1792 + (size_t)i * 32 + wcol;
#pragma unroll
    for (int c = 0; c < 64; ++c) xr[c] = xp[(size_t)c * 57344];

    float* outb = qkv + (size_t)b * 128 * 56;

    for (int oo = 0; oo < 32; ++oo) {
        const int o = wave * 32 + oo;           // uniform -> scalar loads of w row
        const float* wr = w + o * 64;
        float acc = 0.f;
#pragma unroll
        for (int c = 0; c < 64; ++c) acc = fmaf(wr[c], xr[c], acc);

        float val = (lane < 56) ? acc : 0.f;
        if (lane < 56) outb[o * 56 + lane] = acc;

        float s1 = val, s2 = val * val;
#pragma unroll
        for (int off = 32; off > 0; off >>= 1) {
            s1 += __shfl_xor(s1, off);
            s2 += __shfl_xor(s2, off);
        }
        if (lane == 0) {
            atomicAdd(&sums[o], s1);
            atomicAdd(&sums[128 + o], s2);
        }
    }
}

// =============== finalize BN: scale/shift from sums ===============
__global__ void k_fin(const float* __restrict__ sums, const float* __restrict__ g,
                      const float* __restrict__ bb, float* __restrict__ prm,
                      int nch, float invN) {
    int c = threadIdx.x;
    if (c >= nch) return;
    float m = sums[c] * invN;
    float v = sums[nch + c] * invN - m * m;
    float sc = g[c] * rsqrtf(v + EPS);
    prm[c] = sc;
    prm[nch + c] = bb[c] - m * sc;
}

// =============== K3: sim (qk/qr/kr) statistics ===============
__global__ __launch_bounds__(256) void k_sim(const float* __restrict__ qkv,
                                             const float* __restrict__ rel,
                                             const float* __restrict__ prmQ,
                                             float* __restrict__ sums) {
    const int bg = blockIdx.x;
    const int b = bg >> 3, g = bg & 7;
    __shared__ float qk8[8 * 56];
    __shared__ float r8[8 * 111];
    __shared__ float red[4 * 6];

    const float* span = qkv + ((size_t)b * 128 + g * 16) * 56;
    for (int idx = threadIdx.x; idx < 448; idx += 256) {
        int ch = g * 16 + idx / 56;
        qk8[idx] = span[idx] * prmQ[ch] + prmQ[128 + ch];
    }
    for (int idx = threadIdx.x; idx < 888; idx += 256) r8[idx] = rel[idx];
    __syncthreads();

    float a0 = 0, a1 = 0, a2 = 0, a3 = 0, a4 = 0, a5 = 0;
    for (int p = threadIdx.x; p < 3136; p += 256) {
        int i = p / 56, j = p - i * 56;
        int dq = i - j + 55, dk = j - i + 55;
        float qkval = 0, qrv = 0, krv = 0;
#pragma unroll
        for (int c = 0; c < 4; ++c) {
            float qc = qk8[c * 56 + i];
            float kc = qk8[(4 + c) * 56 + j];
            qkval = fmaf(qc, kc, qkval);
            qrv = fmaf(qc, r8[c * 111 + dq], qrv);
            krv = fmaf(kc, r8[(4 + c) * 111 + dk], krv);
        }
        a0 += qkval; a1 += qkval * qkval;
        a2 += qrv;   a3 += qrv * qrv;
        a4 += krv;   a5 += krv * krv;
    }
#pragma unroll
    for (int off = 32; off > 0; off >>= 1) {
        a0 += __shfl_xor(a0, off); a1 += __shfl_xor(a1, off);
        a2 += __shfl_xor(a2, off); a3 += __shfl_xor(a3, off);
        a4 += __shfl_xor(a4, off); a5 += __shfl_xor(a5, off);
    }
    int wv = threadIdx.x >> 6;
    if ((threadIdx.x & 63) == 0) {
        red[wv * 6 + 0] = a0; red[wv * 6 + 1] = a1; red[wv * 6 + 2] = a2;
        red[wv * 6 + 3] = a3; red[wv * 6 + 4] = a4; red[wv * 6 + 5] = a5;
    }
    __syncthreads();
    if (threadIdx.x == 0) {
        float t0 = red[0] + red[6] + red[12] + red[18];
        float t1 = red[1] + red[7] + red[13] + red[19];
        float t2 = red[2] + red[8] + red[14] + red[20];
        float t3 = red[3] + red[9] + red[15] + red[21];
        float t4 = red[4] + red[10] + red[16] + red[22];
        float t5 = red[5] + red[11] + red[17] + red[23];
        atomicAdd(&sums[g], t0);       atomicAdd(&sums[24 + g], t1);
        atomicAdd(&sums[8 + g], t2);   atomicAdd(&sums[24 + 8 + g], t3);
        atomicAdd(&sums[16 + g], t4);  atomicAdd(&sums[24 + 16 + g], t5);
    }
}

// =============== K5: sim -> softmax -> sv/sve (in-place), + out stats ===============
__global__ __launch_bounds__(256) void k_main(float* __restrict__ qkv,
                                              const float* __restrict__ rel,
                                              const float* __restrict__ prmQ,
                                              const float* __restrict__ prmS,
                                              float* __restrict__ sums) {
    const int bg = blockIdx.x;
    const int b = bg >> 3, g = bg & 7;
    __shared__ float qkv16[16 * 56];
    __shared__ float r16[16 * 111];
    __shared__ float sm[56 * 57];
    __shared__ float osum[16], osq[16];

    float* span = qkv + ((size_t)b * 128 + g * 16) * 56;
    for (int idx = threadIdx.x; idx < 896; idx += 256) {
        int ch = g * 16 + idx / 56;
        qkv16[idx] = span[idx] * prmQ[ch] + prmQ[128 + ch];
    }
    for (int idx = threadIdx.x; idx < 1776; idx += 256) r16[idx] = rel[idx];
    if (threadIdx.x < 16) { osum[threadIdx.x] = 0.f; osq[threadIdx.x] = 0.f; }
    __syncthreads();

    const float sc_qk = prmS[g],      sh_qk = prmS[24 + g];
    const float sc_qr = prmS[8 + g],  sh_qr = prmS[24 + 8 + g];
    const float sc_kr = prmS[16 + g], sh_kr = prmS[24 + 16 + g];

    for (int p = threadIdx.x; p < 3136; p += 256) {
        int i = p / 56, j = p - i * 56;
        int dq = i - j + 55, dk = j - i + 55;
        float qkval = 0, qrv = 0, krv = 0;
#pragma unroll
        for (int c = 0; c < 4; ++c) {
            float qc = qkv16[c * 56 + i];
            float kc = qkv16[(4 + c) * 56 + j];
            qkval = fmaf(qc, kc, qkval);
            qrv = fmaf(qc, r16[c * 111 + dq], qrv);
            krv = fmaf(kc, r16[(4 + c) * 111 + dk], krv);
        }
        sm[i * 57 + j] = qkval * sc_qk + sh_qk + qrv * sc_qr + sh_qr + krv * sc_kr + sh_kr;
    }
    __syncthreads();

    // softmax over j for each row i; wave wv handles rows [wv*14, wv*14+14)
    const int lane = threadIdx.x & 63, wv = threadIdx.x >> 6;
    for (int r = 0; r < 14; ++r) {
        int i = wv * 14 + r;
        float v = (lane < 56) ? sm[i * 57 + lane] : -INFINITY;
        float m = v;
#pragma unroll
        for (int off = 32; off > 0; off >>= 1) m = fmaxf(m, __shfl_xor(m, off));
        float e = (lane < 56) ? expf(v - m) : 0.f;
        float ss = e;
#pragma unroll
        for (int off = 32; off > 0; off >>= 1) ss += __shfl_xor(ss, off);
        if (lane < 56) sm[i * 57 + lane] = e / ss;
    }
    __syncthreads();

    // sv, sve; write in place over this block's own qkv span
    for (int p = threadIdx.x; p < 448; p += 256) {
        int c = p / 56, i = p - c * 56;
        const float* vrow = &qkv16[(8 + c) * 56];
        const float* rrow = &r16[(8 + c) * 111];
        float sv = 0, sve = 0;
        for (int j = 0; j < 56; ++j) {
            float sij = sm[i * 57 + j];
            sv = fmaf(sij, vrow[j], sv);
            sve = fmaf(sij, rrow[i - j + 55], sve);
        }
        span[(c * 2 + 0) * 56 + i] = sv;
        span[(c * 2 + 1) * 56 + i] = sve;
        atomicAdd(&osum[c * 2], sv);      atomicAdd(&osq[c * 2], sv * sv);
        atomicAdd(&osum[c * 2 + 1], sve); atomicAdd(&osq[c * 2 + 1], sve * sve);
    }
    __syncthreads();
    if (threadIdx.x < 16) {
        int o = g * 16 + threadIdx.x;
        atomicAdd(&sums[o], osum[threadIdx.x]);
        atomicAdd(&sums[128 + o], osq[threadIdx.x]);
    }
}

// =============== K7: out BN + channel-pair sum + transpose ===============
__global__ __launch_bounds__(256) void k_out(const float* __restrict__ so,
                                             const float* __restrict__ prmO,
                                             float* __restrict__ out) {
    int idx = blockIdx.x * 256 + threadIdx.x;
    if (idx >= 3670016) return;
    int wcol = idx & 31;
    int t = idx >> 5;
    int i = t % 56; t /= 56;
    int s = t & 31;
    int p = t >> 5;
    int b = s * 32 + wcol;
    int o0 = 2 * p;
    float v0 = so[((size_t)b * 128 + o0) * 56 + i];
    float v1 = so[((size_t)b * 128 + o0 + 1) * 56 + i];
    out[idx] = v0 * prmO[o0] + prmO[128 + o0] + v1 * prmO[o0 + 1] + prmO[128 + o0 + 1];
}

extern "C" void kernel_launch(void* const* d_in, const int* in_sizes, int n_in,
                              void* d_out, int out_size, void* d_ws, size_t ws_size,
                              hipStream_t stream) {
    const float* x     = (const float*)d_in[0];
    const float* w_qkv = (const float*)d_in[1];
    const float* g_qkv = (const float*)d_in[2];
    const float* b_qkv = (const float*)d_in[3];
    const float* g_sim = (const float*)d_in[4];
    const float* b_sim = (const float*)d_in[5];
    const float* g_out = (const float*)d_in[6];
    const float* b_out = (const float*)d_in[7];
    const float* rel   = (const float*)d_in[8];
    float* out = (float*)d_out;

    float* ws   = (float*)d_ws;
    float* qkv  = ws;                  // 7340032 floats
    float* sums = ws + 7340032;        // 560: qkv[256] | sim[48] | out[256]
    float* prm  = ws + 7340032 + 560;  // 560: qkvP[256] | simP[48] | outP[256]

    hipMemsetAsync(sums, 0, 560 * sizeof(float), stream);

    k_qkv<<<1024, 256, 0, stream>>>(x, w_qkv, qkv, sums);
    k_fin<<<1, 128, 0, stream>>>(sums, g_qkv, b_qkv, prm, 128, 1.f / 57344.f);
    k_sim<<<8192, 256, 0, stream>>>(qkv, rel, prm, sums + 256);
    k_fin<<<1, 32, 0, stream>>>(sums + 256, g_sim, b_sim, prm + 256, 24, 1.f / 3211264.f);
    k_main<<<8192, 256, 0, stream>>>(qkv, rel, prm, prm + 256, sums + 304);
    k_fin<<<1, 128, 0, stream>>>(sums + 304, g_out, b_out, prm + 304, 128, 1.f / 57344.f);
    k_out<<<14336, 256, 0, stream>>>(qkv, prm + 304, out);
}

// Round 2
// 597.925 us; speedup vs baseline: 1.6725x; 1.6725x over previous
//
#include <hip/hip_runtime.h>
#include <math.h>

#define EPS 1e-5f

// ---------------- workspace layout (floats) ----------------
// [0, 7340032)            qkv buffer, later overwritten in-place with "so"
// [7340032, +560)         sums: qkv[128+128] | sim[24+24] | out[128+128]
// [+560, +1120)           params: qkvP[256] | simP[48] | outP[256]

// =============== K1: tiled GEMM, fused transpose-write + stats ===============
// qkv[((s*32+wcol)*128+o)*56+i] = sum_c w[o][c] * x[c][s][i][wcol]
__global__ __launch_bounds__(256) void k_qkv2(const float* __restrict__ x,
                                              const float* __restrict__ w,
                                              float* __restrict__ qkv,
                                              float* __restrict__ sums) {
    __shared__ __align__(16) float X[64 * 256];  // 64 KB
    __shared__ float T[8 * 264];                 // 8.4 KB transpose tile (pad 1/32)
    const int t = threadIdx.x;
    const int m0 = blockIdx.x << 8;              // 224 blocks * 256 m
    const int s = m0 / 1792;
    const int i0 = (m0 - s * 1792) >> 5;         // 8 i-values per block

    // stage X[64][256] coalesced (each wave-load = one 1KB contiguous row)
    const float* xb = x + m0;
#pragma unroll
    for (int j = 0; j < 16; ++j) {
        int f = (j << 8) + t;
        int c = f >> 6, col = (f & 63) << 2;
        *(float4*)&X[(c << 8) + col] = *(const float4*)&xb[(size_t)c * 57344 + col];
    }
    __syncthreads();

    float* qb = qkv + (size_t)s * 229376 + i0;

    for (int oc = 0; oc < 16; ++oc) {
        const int o0 = oc << 3;
        const float* wp = w + (o0 << 6);
        float acc[8] = {0, 0, 0, 0, 0, 0, 0, 0};
        for (int c = 0; c < 64; ++c) {
            float xv = X[(c << 8) + t];
#pragma unroll
            for (int k = 0; k < 8; ++k) acc[k] = fmaf(wp[(k << 6) + c], xv, acc[k]);
        }
        __syncthreads();                          // prior T readers done
#pragma unroll
        for (int k = 0; k < 8; ++k) T[k * 264 + t + (t >> 5)] = acc[k];
        __syncthreads();
        // write 2048 floats: runs of 8 i (32B), wcol uniform per wave
#pragma unroll
        for (int e = 0; e < 8; ++e) {
            int flat = (e << 8) + t;
            int wcol = flat >> 6, oo = (flat >> 3) & 7, il = flat & 7;
            int mm = (il << 5) + wcol;
            qb[(size_t)wcol * 7168 + (o0 + oo) * 56 + il] = T[oo * 264 + mm + (mm >> 5)];
        }
        // stats from the T tile: 8 rows x (32 parts x 8 elems)
        {
            int row = t >> 5, part = t & 31;
            float s1 = 0.f, s2 = 0.f;
#pragma unroll
            for (int e = 0; e < 8; ++e) {
                int mm = (part << 3) + e;
                float v = T[row * 264 + mm + (mm >> 5)];
                s1 += v; s2 += v * v;
            }
#pragma unroll
            for (int off = 16; off > 0; off >>= 1) {
                s1 += __shfl_xor(s1, off);
                s2 += __shfl_xor(s2, off);
            }
            if (part == 0) {
                atomicAdd(&sums[o0 + row], s1);
                atomicAdd(&sums[128 + o0 + row], s2);
            }
        }
    }
}

// =============== finalize BN: scale/shift from sums ===============
__global__ void k_fin(const float* __restrict__ sums, const float* __restrict__ g,
                      const float* __restrict__ bb, float* __restrict__ prm,
                      int nch, float invN) {
    int c = threadIdx.x;
    if (c >= nch) return;
    float m = sums[c] * invN;
    float v = sums[nch + c] * invN - m * m;
    float sc = g[c] * rsqrtf(v + EPS);
    prm[c] = sc;
    prm[nch + c] = bb[c] - m * sc;
}

// =============== K3: sim (qk/qr/kr) statistics ===============
__global__ __launch_bounds__(256) void k_sim(const float* __restrict__ qkv,
                                             const float* __restrict__ rel,
                                             const float* __restrict__ prmQ,
                                             float* __restrict__ sums) {
    const int bg = blockIdx.x;
    const int b = bg >> 3, g = bg & 7;
    __shared__ float qk8[8 * 56];
    __shared__ float r8[8 * 111];
    __shared__ float red[4 * 6];

    const float* span = qkv + ((size_t)b * 128 + g * 16) * 56;
    for (int idx = threadIdx.x; idx < 448; idx += 256) {
        int ch = g * 16 + idx / 56;
        qk8[idx] = span[idx] * prmQ[ch] + prmQ[128 + ch];
    }
    for (int idx = threadIdx.x; idx < 888; idx += 256) r8[idx] = rel[idx];
    __syncthreads();

    float a0 = 0, a1 = 0, a2 = 0, a3 = 0, a4 = 0, a5 = 0;
    for (int p = threadIdx.x; p < 3136; p += 256) {
        int i = p / 56, j = p - i * 56;
        int dq = i - j + 55, dk = j - i + 55;
        float qkval = 0, qrv = 0, krv = 0;
#pragma unroll
        for (int c = 0; c < 4; ++c) {
            float qc = qk8[c * 56 + i];
            float kc = qk8[(4 + c) * 56 + j];
            qkval = fmaf(qc, kc, qkval);
            qrv = fmaf(qc, r8[c * 111 + dq], qrv);
            krv = fmaf(kc, r8[(4 + c) * 111 + dk], krv);
        }
        a0 += qkval; a1 += qkval * qkval;
        a2 += qrv;   a3 += qrv * qrv;
        a4 += krv;   a5 += krv * krv;
    }
#pragma unroll
    for (int off = 32; off > 0; off >>= 1) {
        a0 += __shfl_xor(a0, off); a1 += __shfl_xor(a1, off);
        a2 += __shfl_xor(a2, off); a3 += __shfl_xor(a3, off);
        a4 += __shfl_xor(a4, off); a5 += __shfl_xor(a5, off);
    }
    int wv = threadIdx.x >> 6;
    if ((threadIdx.x & 63) == 0) {
        red[wv * 6 + 0] = a0; red[wv * 6 + 1] = a1; red[wv * 6 + 2] = a2;
        red[wv * 6 + 3] = a3; red[wv * 6 + 4] = a4; red[wv * 6 + 5] = a5;
    }
    __syncthreads();
    if (threadIdx.x == 0) {
        float t0 = red[0] + red[6] + red[12] + red[18];
        float t1 = red[1] + red[7] + red[13] + red[19];
        float t2 = red[2] + red[8] + red[14] + red[20];
        float t3 = red[3] + red[9] + red[15] + red[21];
        float t4 = red[4] + red[10] + red[16] + red[22];
        float t5 = red[5] + red[11] + red[17] + red[23];
        atomicAdd(&sums[g], t0);       atomicAdd(&sums[24 + g], t1);
        atomicAdd(&sums[8 + g], t2);   atomicAdd(&sums[24 + 8 + g], t3);
        atomicAdd(&sums[16 + g], t4);  atomicAdd(&sums[24 + 16 + g], t5);
    }
}

// =============== K5: sim -> softmax -> sv/sve (in-place) ===============
__global__ __launch_bounds__(256) void k_main(float* __restrict__ qkv,
                                              const float* __restrict__ rel,
                                              const float* __restrict__ prmQ,
                                              const float* __restrict__ prmS) {
    const int bg = blockIdx.x;
    const int b = bg >> 3, g = bg & 7;
    __shared__ float qkv16[16 * 56];
    __shared__ float r16[16 * 111];
    __shared__ float sm[56 * 57];

    float* span = qkv + ((size_t)b * 128 + g * 16) * 56;
    for (int idx = threadIdx.x; idx < 896; idx += 256) {
        int ch = g * 16 + idx / 56;
        qkv16[idx] = span[idx] * prmQ[ch] + prmQ[128 + ch];
    }
    for (int idx = threadIdx.x; idx < 1776; idx += 256) r16[idx] = rel[idx];
    __syncthreads();

    const float sc_qk = prmS[g],      sh_qk = prmS[24 + g];
    const float sc_qr = prmS[8 + g],  sh_qr = prmS[24 + 8 + g];
    const float sc_kr = prmS[16 + g], sh_kr = prmS[24 + 16 + g];

    for (int p = threadIdx.x; p < 3136; p += 256) {
        int i = p / 56, j = p - i * 56;
        int dq = i - j + 55, dk = j - i + 55;
        float qkval = 0, qrv = 0, krv = 0;
#pragma unroll
        for (int c = 0; c < 4; ++c) {
            float qc = qkv16[c * 56 + i];
            float kc = qkv16[(4 + c) * 56 + j];
            qkval = fmaf(qc, kc, qkval);
            qrv = fmaf(qc, r16[c * 111 + dq], qrv);
            krv = fmaf(kc, r16[(4 + c) * 111 + dk], krv);
        }
        sm[i * 57 + j] = qkval * sc_qk + sh_qk + qrv * sc_qr + sh_qr + krv * sc_kr + sh_kr;
    }
    __syncthreads();

    // softmax over j for each row i; wave wv handles rows [wv*14, wv*14+14)
    const int lane = threadIdx.x & 63, wv = threadIdx.x >> 6;
    for (int r = 0; r < 14; ++r) {
        int i = wv * 14 + r;
        float v = (lane < 56) ? sm[i * 57 + lane] : -INFINITY;
        float m = v;
#pragma unroll
        for (int off = 32; off > 0; off >>= 1) m = fmaxf(m, __shfl_xor(m, off));
        float e = (lane < 56) ? __expf(v - m) : 0.f;
        float ss = e;
#pragma unroll
        for (int off = 32; off > 0; off >>= 1) ss += __shfl_xor(ss, off);
        float inv = __builtin_amdgcn_rcpf(ss);
        if (lane < 56) sm[i * 57 + lane] = e * inv;
    }
    __syncthreads();

    // sv, sve; write in place over this block's own qkv span
    for (int p = threadIdx.x; p < 448; p += 256) {
        int c = p / 56, i = p - c * 56;
        const float* vrow = &qkv16[(8 + c) * 56];
        const float* rrow = &r16[(8 + c) * 111];
        float sv = 0, sve = 0;
        for (int j = 0; j < 56; ++j) {
            float sij = sm[i * 57 + j];
            sv = fmaf(sij, vrow[j], sv);
            sve = fmaf(sij, rrow[i - j + 55], sve);
        }
        span[(c * 2 + 0) * 56 + i] = sv;
        span[(c * 2 + 1) * 56 + i] = sve;
    }
}

// =============== K6: out stats (coalesced pass over so) ===============
__global__ __launch_bounds__(256) void k_stats(const float* __restrict__ so,
                                               float* __restrict__ sums) {
    const int t = threadIdx.x;
    const int o = blockIdx.x >> 3;
    const int b0 = (blockIdx.x & 7) << 7;
    float s1 = 0.f, s2 = 0.f;
#pragma unroll
    for (int j = 0; j < 7; ++j) {
        int f = (j << 8) + t;                 // f4 index < 1792
        int row = f / 14, q = f - row * 14;
        const float* src = so + ((size_t)(b0 + row) * 128 + o) * 56 + (q << 2);
        float4 v = *(const float4*)src;
        s1 += v.x + v.y + v.z + v.w;
        s2 += v.x * v.x + v.y * v.y + v.z * v.z + v.w * v.w;
    }
#pragma unroll
    for (int off = 32; off > 0; off >>= 1) { s1 += __shfl_xor(s1, off); s2 += __shfl_xor(s2, off); }
    if ((t & 63) == 0) { atomicAdd(&sums[o], s1); atomicAdd(&sums[128 + o], s2); }
}

// =============== K7: out BN + channel-pair sum + transpose (LDS tiled) ===============
__global__ __launch_bounds__(256) void k_out2(const float* __restrict__ so,
                                              const float* __restrict__ prmO,
                                              float* __restrict__ out) {
    __shared__ float L[128 * 61];
    const int t = threadIdx.x;
    const int s = blockIdx.x & 31;
    const int pc = blockIdx.x >> 5;
    const int o0 = pc << 2;  // 4 so-channels
    const int p0 = pc << 1;  // 2 out-channels

#pragma unroll
    for (int j = 0; j < 7; ++j) {
        int f = (j << 8) + t;                 // f4 index < 1792
        int row = f / 14, q = f - row * 14;
        int ch = row >> 5, wcol = row & 31;
        const float* src = so + ((size_t)(s * 32 + wcol) * 128 + o0 + ch) * 56 + (q << 2);
        float4 v = *(const float4*)src;
        float* dst = &L[row * 61 + (q << 2)];
        dst[0] = v.x; dst[1] = v.y; dst[2] = v.z; dst[3] = v.w;
    }
    __syncthreads();
#pragma unroll
    for (int j = 0; j < 14; ++j) {
        int flat = (j << 8) + t;              // < 3584
        int wcol = flat & 31, r = flat >> 5;
        int i = r % 56, pp = r / 56;
        float v0 = L[((pp * 2) * 32 + wcol) * 61 + i];
        float v1 = L[((pp * 2 + 1) * 32 + wcol) * 61 + i];
        float sc0 = prmO[o0 + (pp << 1)],     sh0 = prmO[128 + o0 + (pp << 1)];
        float sc1 = prmO[o0 + (pp << 1) + 1], sh1 = prmO[128 + o0 + (pp << 1) + 1];
        out[(((size_t)(p0 + pp) * 32 + s) * 56 + i) * 32 + wcol] =
            v0 * sc0 + sh0 + v1 * sc1 + sh1;
    }
}

extern "C" void kernel_launch(void* const* d_in, const int* in_sizes, int n_in,
                              void* d_out, int out_size, void* d_ws, size_t ws_size,
                              hipStream_t stream) {
    const float* x     = (const float*)d_in[0];
    const float* w_qkv = (const float*)d_in[1];
    const float* g_qkv = (const float*)d_in[2];
    const float* b_qkv = (const float*)d_in[3];
    const float* g_sim = (const float*)d_in[4];
    const float* b_sim = (const float*)d_in[5];
    const float* g_out = (const float*)d_in[6];
    const float* b_out = (const float*)d_in[7];
    const float* rel   = (const float*)d_in[8];
    float* out = (float*)d_out;

    float* ws   = (float*)d_ws;
    float* qkv  = ws;                  // 7340032 floats
    float* sums = ws + 7340032;        // 560
    float* prm  = ws + 7340032 + 560;  // 560

    hipMemsetAsync(sums, 0, 560 * sizeof(float), stream);

    k_qkv2<<<224, 256, 0, stream>>>(x, w_qkv, qkv, sums);
    k_fin<<<1, 128, 0, stream>>>(sums, g_qkv, b_qkv, prm, 128, 1.f / 57344.f);
    k_sim<<<8192, 256, 0, stream>>>(qkv, rel, prm, sums + 256);
    k_fin<<<1, 32, 0, stream>>>(sums + 256, g_sim, b_sim, prm + 256, 24, 1.f / 3211264.f);
    k_main<<<8192, 256, 0, stream>>>(qkv, rel, prm, prm + 256);
    k_stats<<<1024, 256, 0, stream>>>(qkv, sums + 304);
    k_fin<<<1, 128, 0, stream>>>(sums + 304, g_out, b_out, prm + 304, 128, 1.f / 57344.f);
    k_out2<<<1024, 256, 0, stream>>>(qkv, prm + 304, out);
}

// Round 3
// 277.032 us; speedup vs baseline: 3.6098x; 2.1583x over previous
//
#include <hip/hip_runtime.h>
#include <math.h>

#define EPS 1e-5f

// ---------------- workspace layout (floats) ----------------
// qkv   : [0, 7340032)   qkv buffer, later overwritten in-place with "so"
// P     : +57344         partials: qkv [256][224], later reused as sim [48][1024]
// sumsO : +256           out stats (atomic, 8-way contention only)
// prm   : +560           qkvP[256] | simP[48] | outP[256]
// tab   : +2240          Rq[4][56] Rk[4][56] Sq[16][56] Sk[16][56]

// =============== K0: window-sum tables from rel ===============
__global__ __launch_bounds__(256) void k_prep(const float* __restrict__ rel,
                                              float* __restrict__ tab) {
    __shared__ float r[16 * 111];
    for (int idx = threadIdx.x; idx < 1776; idx += 256) r[idx] = rel[idx];
    __syncthreads();
    for (int o = threadIdx.x; o < 2240; o += 256) {
        int row = o / 56, i = o - row * 56;
        float s = 0.f;
        if (row < 8) {                       // Rq rows 0..3 (rel 0..3), Rk rows 4..7 (rel 4..7)
            const float* rr = &r[row * 111];
#pragma unroll
            for (int u = 0; u < 56; ++u) s += rr[i + u];
        } else if (row < 24) {               // Sq pair p: rel rows (p>>2, p&3)
            int p = row - 8;
            const float* ra = &r[(p >> 2) * 111];
            const float* rb = &r[(p & 3) * 111];
#pragma unroll
            for (int u = 0; u < 56; ++u) s = fmaf(ra[i + u], rb[i + u], s);
        } else {                             // Sk pair: rel rows (4+(p>>2), 4+(p&3))
            int p = row - 24;
            const float* ra = &r[(4 + (p >> 2)) * 111];
            const float* rb = &r[(4 + (p & 3)) * 111];
#pragma unroll
            for (int u = 0; u < 56; ++u) s = fmaf(ra[i + u], rb[i + u], s);
        }
        tab[o] = s;
    }
}

// =============== K1: tiled GEMM, fused transpose-write + partial stats ===============
__global__ __launch_bounds__(256) void k_qkv2(const float* __restrict__ x,
                                              const float* __restrict__ w,
                                              float* __restrict__ qkv,
                                              float* __restrict__ P) {
    __shared__ __align__(16) float X[64 * 256];
    __shared__ float T[8 * 264];
    const int t = threadIdx.x;
    const int m0 = blockIdx.x << 8;
    const int s = m0 / 1792;
    const int i0 = (m0 - s * 1792) >> 5;

    const float* xb = x + m0;
#pragma unroll
    for (int j = 0; j < 16; ++j) {
        int f = (j << 8) + t;
        int c = f >> 6, col = (f & 63) << 2;
        *(float4*)&X[(c << 8) + col] = *(const float4*)&xb[(size_t)c * 57344 + col];
    }
    __syncthreads();

    float* qb = qkv + (size_t)s * 229376 + i0;

    for (int oc = 0; oc < 16; ++oc) {
        const int o0 = oc << 3;
        const float* wp = w + (o0 << 6);
        float acc[8] = {0, 0, 0, 0, 0, 0, 0, 0};
        for (int c = 0; c < 64; ++c) {
            float xv = X[(c << 8) + t];
#pragma unroll
            for (int k = 0; k < 8; ++k) acc[k] = fmaf(wp[(k << 6) + c], xv, acc[k]);
        }
        __syncthreads();
#pragma unroll
        for (int k = 0; k < 8; ++k) T[k * 264 + t + (t >> 5)] = acc[k];
        __syncthreads();
#pragma unroll
        for (int e = 0; e < 8; ++e) {
            int flat = (e << 8) + t;
            int wcol = flat >> 6, oo = (flat >> 3) & 7, il = flat & 7;
            int mm = (il << 5) + wcol;
            qb[(size_t)wcol * 7168 + (o0 + oo) * 56 + il] = T[oo * 264 + mm + (mm >> 5)];
        }
        {
            int row = t >> 5, part = t & 31;
            float s1 = 0.f, s2 = 0.f;
#pragma unroll
            for (int e = 0; e < 8; ++e) {
                int mm = (part << 3) + e;
                float v = T[row * 264 + mm + (mm >> 5)];
                s1 += v; s2 += v * v;
            }
#pragma unroll
            for (int off = 16; off > 0; off >>= 1) {
                s1 += __shfl_xor(s1, off);
                s2 += __shfl_xor(s2, off);
            }
            if (part == 0) {
                P[(o0 + row) * 224 + blockIdx.x] = s1;
                P[(128 + o0 + row) * 224 + blockIdx.x] = s2;
            }
        }
    }
}

// =============== coalesced partial reduction -> BN params ===============
__global__ __launch_bounds__(64) void k_fin_red(const float* __restrict__ P,
                                                const float* __restrict__ g,
                                                const float* __restrict__ bb,
                                                float* __restrict__ prm,
                                                int nch, int npart, float invN) {
    const int c = blockIdx.x, lane = threadIdx.x;
    const float* r1 = P + (size_t)c * npart;
    const float* r2 = P + (size_t)(nch + c) * npart;
    float s1 = 0.f, s2 = 0.f;
    for (int p = lane; p < npart; p += 64) { s1 += r1[p]; s2 += r2[p]; }
#pragma unroll
    for (int off = 32; off > 0; off >>= 1) { s1 += __shfl_xor(s1, off); s2 += __shfl_xor(s2, off); }
    if (lane == 0) {
        float m = s1 * invN;
        float v = s2 * invN - m * m;
        float sc = g[c] * rsqrtf(v + EPS);
        prm[c] = sc;
        prm[nch + c] = bb[c] - m * sc;
    }
}

// =============== original small finalize (for out BN, atomic sums) ===============
__global__ void k_fin(const float* __restrict__ sums, const float* __restrict__ g,
                      const float* __restrict__ bb, float* __restrict__ prm,
                      int nch, float invN) {
    int c = threadIdx.x;
    if (c >= nch) return;
    float m = sums[c] * invN;
    float v = sums[nch + c] * invN - m * m;
    float sc = g[c] * rsqrtf(v + EPS);
    prm[c] = sc;
    prm[nch + c] = bb[c] - m * sc;
}

// =============== K3: algebraic sim statistics (atomic-free) ===============
// per b: for each g, 6 stats via Gram matrices + precomputed R/S tables
__global__ __launch_bounds__(256) void k_sim2(const float* __restrict__ qkv,
                                              const float* __restrict__ prmQ,
                                              const float* __restrict__ tab,
                                              float* __restrict__ P) {
    __shared__ float qn[8 * 8 * 57];   // [g][c][57] normalized q,k
    __shared__ float T[40 * 57];       // Sq rows 0..15, Sk 16..31, Rq 32..35, Rk 36..39
    __shared__ float red[8 * 6];
    const int t = threadIdx.x, b = blockIdx.x;

    const float* span = qkv + (size_t)b * 7168;
    for (int idx = t; idx < 3584; idx += 256) {
        int g = idx / 448, r = idx - g * 448, c = r / 56, i = r - c * 56;
        int ch = g * 16 + c;
        qn[(g * 8 + c) * 57 + i] = span[g * 896 + r] * prmQ[ch] + prmQ[128 + ch];
    }
    for (int idx = t; idx < 2240; idx += 256) {
        int row = idx / 56, i = idx - row * 56;
        int lr = (row < 8) ? (32 + row) : (row - 8);
        T[lr * 57 + i] = tab[idx];
    }
    __syncthreads();

    const int g = t >> 5, u = t & 31;
    const int half = (u < 16) ? 0 : 4;
    const float* rowA = &qn[g * 456 + (half + ((u >> 2) & 3)) * 57];
    const float* rowB = &qn[g * 456 + (half + (u & 3)) * 57];
    const float* tabS = &T[u * 57];
    const float* tabR = &T[(32 + half + (u & 3)) * 57];

    float gram = 0.f, wgt = 0.f, lin1 = 0.f, lin2 = 0.f;
#pragma unroll
    for (int i = 0; i < 56; ++i) {
        float a = rowA[i], b2 = rowB[i], p = a * b2;
        gram += p;
        wgt = fmaf(p, tabS[i], wgt);
        lin1 += b2;
        lin2 = fmaf(b2, tabR[i], lin2);
    }
    float linP = __shfl_xor(lin1, 16);
    float gramP = __shfl_xor(gram, 16);
    float v0 = (u < 4) ? lin1 * linP : 0.f;              // qk sum
    float v1 = (u < 16) ? gram * gramP : 0.f;            // qk sq
    float v2 = (u < 4) ? lin2 : 0.f;                     // qr sum
    float v3 = (u < 16) ? wgt : 0.f;                     // qr sq
    float v4 = (u >= 16 && u < 20) ? lin2 : 0.f;         // kr sum
    float v5 = (u >= 16) ? wgt : 0.f;                    // kr sq
#pragma unroll
    for (int off = 16; off > 0; off >>= 1) {
        v0 += __shfl_xor(v0, off); v1 += __shfl_xor(v1, off);
        v2 += __shfl_xor(v2, off); v3 += __shfl_xor(v3, off);
        v4 += __shfl_xor(v4, off); v5 += __shfl_xor(v5, off);
    }
    if (u == 0) {
        red[g * 6 + 0] = v0; red[g * 6 + 1] = v1; red[g * 6 + 2] = v2;
        red[g * 6 + 3] = v3; red[g * 6 + 4] = v4; red[g * 6 + 5] = v5;
    }
    __syncthreads();
    if (t < 48) {
        int g2 = t / 6, s = t - g2 * 6;
        int row = ((s & 1) ? 24 : 0) + (s >> 1) * 8 + g2;   // sums rows 0..23, sqs 24..47
        P[(size_t)row * 1024 + b] = red[g2 * 6 + s];
    }
}

// =============== K5: sim -> softmax -> sv/sve (in-place) ===============
__global__ __launch_bounds__(256) void k_main(float* __restrict__ qkv,
                                              const float* __restrict__ rel,
                                              const float* __restrict__ prmQ,
                                              const float* __restrict__ prmS) {
    const int bg = blockIdx.x;
    const int b = bg >> 3, g = bg & 7;
    __shared__ float qkv16[16 * 56];
    __shared__ float r16[16 * 111];
    __shared__ float sm[56 * 57];

    float* span = qkv + ((size_t)b * 128 + g * 16) * 56;
    for (int idx = threadIdx.x; idx < 896; idx += 256) {
        int ch = g * 16 + idx / 56;
        qkv16[idx] = span[idx] * prmQ[ch] + prmQ[128 + ch];
    }
    for (int idx = threadIdx.x; idx < 1776; idx += 256) r16[idx] = rel[idx];
    __syncthreads();

    const float sc_qk = prmS[g],      sh_qk = prmS[24 + g];
    const float sc_qr = prmS[8 + g],  sh_qr = prmS[24 + 8 + g];
    const float sc_kr = prmS[16 + g], sh_kr = prmS[24 + 16 + g];

    for (int p = threadIdx.x; p < 3136; p += 256) {
        int i = p / 56, j = p - i * 56;
        int dq = i - j + 55, dk = j - i + 55;
        float qkval = 0, qrv = 0, krv = 0;
#pragma unroll
        for (int c = 0; c < 4; ++c) {
            float qc = qkv16[c * 56 + i];
            float kc = qkv16[(4 + c) * 56 + j];
            qkval = fmaf(qc, kc, qkval);
            qrv = fmaf(qc, r16[c * 111 + dq], qrv);
            krv = fmaf(kc, r16[(4 + c) * 111 + dk], krv);
        }
        sm[i * 57 + j] = qkval * sc_qk + sh_qk + qrv * sc_qr + sh_qr + krv * sc_kr + sh_kr;
    }
    __syncthreads();

    const int lane = threadIdx.x & 63, wv = threadIdx.x >> 6;
    for (int r = 0; r < 14; ++r) {
        int i = wv * 14 + r;
        float v = (lane < 56) ? sm[i * 57 + lane] : -INFINITY;
        float m = v;
#pragma unroll
        for (int off = 32; off > 0; off >>= 1) m = fmaxf(m, __shfl_xor(m, off));
        float e = (lane < 56) ? __expf(v - m) : 0.f;
        float ss = e;
#pragma unroll
        for (int off = 32; off > 0; off >>= 1) ss += __shfl_xor(ss, off);
        float inv = __builtin_amdgcn_rcpf(ss);
        if (lane < 56) sm[i * 57 + lane] = e * inv;
    }
    __syncthreads();

    for (int p = threadIdx.x; p < 448; p += 256) {
        int c = p / 56, i = p - c * 56;
        const float* vrow = &qkv16[(8 + c) * 56];
        const float* rrow = &r16[(8 + c) * 111];
        float sv = 0, sve = 0;
        for (int j = 0; j < 56; ++j) {
            float sij = sm[i * 57 + j];
            sv = fmaf(sij, vrow[j], sv);
            sve = fmaf(sij, rrow[i - j + 55], sve);
        }
        span[(c * 2 + 0) * 56 + i] = sv;
        span[(c * 2 + 1) * 56 + i] = sve;
    }
}

// =============== K6: out stats (coalesced, 8-way atomics only) ===============
__global__ __launch_bounds__(256) void k_stats(const float* __restrict__ so,
                                               float* __restrict__ sums) {
    const int t = threadIdx.x;
    const int o = blockIdx.x >> 3;
    const int b0 = (blockIdx.x & 7) << 7;
    float s1 = 0.f, s2 = 0.f;
#pragma unroll
    for (int j = 0; j < 7; ++j) {
        int f = (j << 8) + t;
        int row = f / 14, q = f - row * 14;
        const float* src = so + ((size_t)(b0 + row) * 128 + o) * 56 + (q << 2);
        float4 v = *(const float4*)src;
        s1 += v.x + v.y + v.z + v.w;
        s2 += v.x * v.x + v.y * v.y + v.z * v.z + v.w * v.w;
    }
#pragma unroll
    for (int off = 32; off > 0; off >>= 1) { s1 += __shfl_xor(s1, off); s2 += __shfl_xor(s2, off); }
    if ((t & 63) == 0) { atomicAdd(&sums[o], s1); atomicAdd(&sums[128 + o], s2); }
}

// =============== K7: out BN + channel-pair sum + transpose (LDS tiled) ===============
__global__ __launch_bounds__(256) void k_out2(const float* __restrict__ so,
                                              const float* __restrict__ prmO,
                                              float* __restrict__ out) {
    __shared__ float L[128 * 61];
    const int t = threadIdx.x;
    const int s = blockIdx.x & 31;
    const int pc = blockIdx.x >> 5;
    const int o0 = pc << 2;
    const int p0 = pc << 1;

#pragma unroll
    for (int j = 0; j < 7; ++j) {
        int f = (j << 8) + t;
        int row = f / 14, q = f - row * 14;
        int ch = row >> 5, wcol = row & 31;
        const float* src = so + ((size_t)(s * 32 + wcol) * 128 + o0 + ch) * 56 + (q << 2);
        float4 v = *(const float4*)src;
        float* dst = &L[row * 61 + (q << 2)];
        dst[0] = v.x; dst[1] = v.y; dst[2] = v.z; dst[3] = v.w;
    }
    __syncthreads();
#pragma unroll
    for (int j = 0; j < 14; ++j) {
        int flat = (j << 8) + t;
        int wcol = flat & 31, r = flat >> 5;
        int i = r % 56, pp = r / 56;
        float v0 = L[((pp * 2) * 32 + wcol) * 61 + i];
        float v1 = L[((pp * 2 + 1) * 32 + wcol) * 61 + i];
        float sc0 = prmO[o0 + (pp << 1)],     sh0 = prmO[128 + o0 + (pp << 1)];
        float sc1 = prmO[o0 + (pp << 1) + 1], sh1 = prmO[128 + o0 + (pp << 1) + 1];
        out[(((size_t)(p0 + pp) * 32 + s) * 56 + i) * 32 + wcol] =
            v0 * sc0 + sh0 + v1 * sc1 + sh1;
    }
}

extern "C" void kernel_launch(void* const* d_in, const int* in_sizes, int n_in,
                              void* d_out, int out_size, void* d_ws, size_t ws_size,
                              hipStream_t stream) {
    const float* x     = (const float*)d_in[0];
    const float* w_qkv = (const float*)d_in[1];
    const float* g_qkv = (const float*)d_in[2];
    const float* b_qkv = (const float*)d_in[3];
    const float* g_sim = (const float*)d_in[4];
    const float* b_sim = (const float*)d_in[5];
    const float* g_out = (const float*)d_in[6];
    const float* b_out = (const float*)d_in[7];
    const float* rel   = (const float*)d_in[8];
    float* out = (float*)d_out;

    float* ws    = (float*)d_ws;
    float* qkv   = ws;                         // 7,340,032
    float* P     = ws + 7340032;               // 57,344 partials (reused)
    float* sumsO = ws + 7340032 + 57344;       // 256
    float* prm   = sumsO + 256;                // 560
    float* tab   = prm + 560;                  // 2,240

    hipMemsetAsync(sumsO, 0, 256 * sizeof(float), stream);

    k_prep<<<1, 256, 0, stream>>>(rel, tab);
    k_qkv2<<<224, 256, 0, stream>>>(x, w_qkv, qkv, P);
    k_fin_red<<<128, 64, 0, stream>>>(P, g_qkv, b_qkv, prm, 128, 224, 1.f / 57344.f);
    k_sim2<<<1024, 256, 0, stream>>>(qkv, prm, tab, P);
    k_fin_red<<<24, 64, 0, stream>>>(P, g_sim, b_sim, prm + 256, 24, 1024, 1.f / 3211264.f);
    k_main<<<8192, 256, 0, stream>>>(qkv, rel, prm, prm + 256);
    k_stats<<<1024, 256, 0, stream>>>(qkv, sumsO);
    k_fin<<<1, 128, 0, stream>>>(sumsO, g_out, b_out, prm + 304, 128, 1.f / 57344.f);
    k_out2<<<1024, 256, 0, stream>>>(qkv, prm + 304, out);
}